// Round 2
// baseline (341.168 us; speedup 1.0000x reference)
//
#include <hip/hip_runtime.h>

#define SEQ   1024
#define EMBED 512
#define NHEAD 64
#define HDIM  8
#define MTOT  4096        // BATCH*SEQ
#define SCALE 0.35355339059327376f   // 1/sqrt(8)

#define BM 128
#define BN 64
#define BK 32

// ---------------------------------------------------------------------------
// Kernel 1: qkv = x @ Wqkv^T  (M=4096, N=1536, K=512), fused quantum epilogue
// Each thread owns a 4x8 micro-tile; its 8 N-columns are 8-aligned => exactly
// one (seg, head): epilogue does cos(t+theta) cumprod and writes qq/kq/vq in
// [B,H,S,D] layout.
// ---------------------------------------------------------------------------
__global__ __launch_bounds__(256)
void qkv_quantum_kernel(const float* __restrict__ x, const float* __restrict__ W,
                        const float* __restrict__ theta,
                        float* __restrict__ qq, float* __restrict__ kq,
                        float* __restrict__ vq)
{
    __shared__ __align__(16) float As[BK][BM + 4];   // [k][m], pad 4 keeps 16B align
    __shared__ __align__(16) float Bs[BK][BN + 4];   // [k][n]

    const int tid   = threadIdx.x;
    const int mt    = blockIdx.x & 31;   // 32 m-tiles (m fastest: W panel reuse in L2)
    const int nt    = blockIdx.x >> 5;   // 24 n-tiles
    const int mbase = mt * BM;
    const int nbase = nt * BN;

    const int rowg = tid >> 3;           // 0..31
    const int c4   = (tid & 7) << 2;     // 0,4,...,28  (k within tile)
    const int m0   = (tid >> 3) << 2;    // 4 rows per thread
    const int n0   = (tid & 7) << 3;     // 8 cols per thread (8-aligned!)

    float acc[4][8];
    #pragma unroll
    for (int i = 0; i < 4; ++i)
        #pragma unroll
        for (int j = 0; j < 8; ++j) acc[i][j] = 0.f;

    for (int k0 = 0; k0 < EMBED; k0 += BK) {
        #pragma unroll
        for (int p = 0; p < 4; ++p) {
            int r = rowg + p * 32;
            const float4 v = *(const float4*)(x + (size_t)(mbase + r) * EMBED + k0 + c4);
            As[c4 + 0][r] = v.x; As[c4 + 1][r] = v.y;
            As[c4 + 2][r] = v.z; As[c4 + 3][r] = v.w;
        }
        #pragma unroll
        for (int p = 0; p < 2; ++p) {
            int r = rowg + p * 32;
            const float4 v = *(const float4*)(W + (size_t)(nbase + r) * EMBED + k0 + c4);
            Bs[c4 + 0][r] = v.x; Bs[c4 + 1][r] = v.y;
            Bs[c4 + 2][r] = v.z; Bs[c4 + 3][r] = v.w;
        }
        __syncthreads();
        #pragma unroll 8
        for (int kk = 0; kk < BK; ++kk) {
            const float4 a4 = *(const float4*)&As[kk][m0];
            const float4 b0 = *(const float4*)&Bs[kk][n0];
            const float4 b1 = *(const float4*)&Bs[kk][n0 + 4];
            const float a[4] = {a4.x, a4.y, a4.z, a4.w};
            const float b[8] = {b0.x, b0.y, b0.z, b0.w, b1.x, b1.y, b1.z, b1.w};
            #pragma unroll
            for (int i = 0; i < 4; ++i)
                #pragma unroll
                for (int j = 0; j < 8; ++j)
                    acc[i][j] = fmaf(a[i], b[j], acc[i][j]);
        }
        __syncthreads();
    }

    // quantum epilogue: c = cos(t + theta), cumprod over d
    const int ng     = nbase + n0;
    const int seg    = ng >> 9;          // 0=q 1=k 2=v
    const int within = ng & 511;
    const int h      = within >> 3;
    float th[8];
    #pragma unroll
    for (int d = 0; d < 8; ++d) th[d] = theta[h * 8 + d];
    float* dst = (seg == 0) ? qq : (seg == 1) ? kq : vq;

    #pragma unroll
    for (int i = 0; i < 4; ++i) {
        const int m = mbase + m0 + i;
        const int b = m >> 10;
        const int s = m & (SEQ - 1);
        float cum = 1.f, o[8];
        #pragma unroll
        for (int d = 0; d < 8; ++d) {
            cum *= __cosf(acc[i][d] + th[d]);
            o[d] = cum;
        }
        float* p = dst + ((size_t)(b * NHEAD + h) * SEQ + s) * HDIM;
        *(float4*)(p)     = make_float4(o[0], o[1], o[2], o[3]);
        *(float4*)(p + 4) = make_float4(o[4], o[5], o[6], o[7]);
    }
}

// ---------------------------------------------------------------------------
// Kernel 2: attention per (b,h). K/V (32KB each) staged in LDS. 256 threads =
// 128 row-groups x 2 k-halves; each thread does 8 q-rows over 512 k-steps.
// Scores bounded (|s|<=2.83) => softmax without max subtraction; partials
// combined across the 2 halves via LDS.
// ---------------------------------------------------------------------------
__global__ __launch_bounds__(256)
void attn_kernel(const float* __restrict__ qq, const float* __restrict__ kq,
                 const float* __restrict__ vq, float* __restrict__ attnbuf)
{
    __shared__ __align__(16) float smem[2 * SEQ * HDIM];   // 64 KB: Ks | Vs
    float* Ks = smem;
    float* Vs = smem + SEQ * HDIM;

    const int tid = threadIdx.x;
    const int bh  = blockIdx.x;            // b*64 + h
    const size_t base = (size_t)bh * SEQ * HDIM;

    const float4* ksrc = (const float4*)(kq + base);
    const float4* vsrc = (const float4*)(vq + base);
    for (int i = tid; i < SEQ * HDIM / 4; i += 256) {
        ((float4*)Ks)[i] = ksrc[i];
        ((float4*)Vs)[i] = vsrc[i];
    }
    __syncthreads();

    const int half = tid & 1;
    const int rt   = tid >> 1;             // 0..127
    const int r0   = rt * 8;

    float q[8][8];
    #pragma unroll
    for (int r = 0; r < 8; ++r) {
        const float* qp = qq + base + (size_t)(r0 + r) * HDIM;
        const float4 v0 = *(const float4*)qp;
        const float4 v1 = *(const float4*)(qp + 4);
        q[r][0] = v0.x; q[r][1] = v0.y; q[r][2] = v0.z; q[r][3] = v0.w;
        q[r][4] = v1.x; q[r][5] = v1.y; q[r][6] = v1.z; q[r][7] = v1.w;
    }

    float den[8];
    float acc[8][8];
    #pragma unroll
    for (int r = 0; r < 8; ++r) {
        den[r] = 0.f;
        #pragma unroll
        for (int d = 0; d < 8; ++d) acc[r][d] = 0.f;
    }

    const int k0 = half * (SEQ / 2);
    #pragma unroll 2
    for (int k = k0; k < k0 + SEQ / 2; ++k) {
        const float* kp = Ks + k * 8;
        const float* vp = Vs + k * 8;
        const float4 ka = *(const float4*)kp,       kb = *(const float4*)(kp + 4);
        const float4 va = *(const float4*)vp,       vb = *(const float4*)(vp + 4);
        const float kv[8] = {ka.x, ka.y, ka.z, ka.w, kb.x, kb.y, kb.z, kb.w};
        const float vv[8] = {va.x, va.y, va.z, va.w, vb.x, vb.y, vb.z, vb.w};
        #pragma unroll
        for (int r = 0; r < 8; ++r) {
            float s = q[r][0] * kv[0];
            #pragma unroll
            for (int d = 1; d < 8; ++d) s = fmaf(q[r][d], kv[d], s);
            const float p = __expf(s * SCALE);
            den[r] += p;
            #pragma unroll
            for (int d = 0; d < 8; ++d) acc[r][d] = fmaf(p, vv[d], acc[r][d]);
        }
    }

    __syncthreads();            // everyone done with Ks/Vs
    // half==1 dumps partials (72 floats per row-group) into smem
    float* ex = smem;
    if (half == 1) {
        float* w = ex + rt * 72;
        #pragma unroll
        for (int r = 0; r < 8; ++r) w[r] = den[r];
        #pragma unroll
        for (int r = 0; r < 8; ++r)
            #pragma unroll
            for (int d = 0; d < 8; ++d) w[8 + r * 8 + d] = acc[r][d];
    }
    __syncthreads();
    if (half == 0) {
        const float* w = ex + rt * 72;
        const int b = bh >> 6, h = bh & 63;
        #pragma unroll
        for (int r = 0; r < 8; ++r) {
            const float inv = 1.f / (den[r] + w[r]);
            float o[8];
            #pragma unroll
            for (int d = 0; d < 8; ++d)
                o[d] = (acc[r][d] + w[8 + r * 8 + d]) * inv;
            float* outp = attnbuf + ((size_t)(b * SEQ + r0 + r)) * EMBED + h * HDIM;
            *(float4*)(outp)     = make_float4(o[0], o[1], o[2], o[3]);
            *(float4*)(outp + 4) = make_float4(o[4], o[5], o[6], o[7]);
        }
    }
}

// ---------------------------------------------------------------------------
// Kernel 3: out = attn @ Wout^T + bout   (M=4096, N=512, K=512)
// ---------------------------------------------------------------------------
__global__ __launch_bounds__(256)
void out_gemm_kernel(const float* __restrict__ A, const float* __restrict__ W,
                     const float* __restrict__ bias, float* __restrict__ out)
{
    __shared__ __align__(16) float As[BK][BM + 4];
    __shared__ __align__(16) float Bs[BK][BN + 4];

    const int tid   = threadIdx.x;
    const int mt    = blockIdx.x & 31;
    const int nt    = blockIdx.x >> 5;   // 0..7
    const int mbase = mt * BM;
    const int nbase = nt * BN;

    const int rowg = tid >> 3;
    const int c4   = (tid & 7) << 2;
    const int m0   = (tid >> 3) << 2;
    const int n0   = (tid & 7) << 3;

    float acc[4][8];
    #pragma unroll
    for (int i = 0; i < 4; ++i)
        #pragma unroll
        for (int j = 0; j < 8; ++j) acc[i][j] = 0.f;

    for (int k0 = 0; k0 < EMBED; k0 += BK) {
        #pragma unroll
        for (int p = 0; p < 4; ++p) {
            int r = rowg + p * 32;
            const float4 v = *(const float4*)(A + (size_t)(mbase + r) * EMBED + k0 + c4);
            As[c4 + 0][r] = v.x; As[c4 + 1][r] = v.y;
            As[c4 + 2][r] = v.z; As[c4 + 3][r] = v.w;
        }
        #pragma unroll
        for (int p = 0; p < 2; ++p) {
            int r = rowg + p * 32;
            const float4 v = *(const float4*)(W + (size_t)(nbase + r) * EMBED + k0 + c4);
            Bs[c4 + 0][r] = v.x; Bs[c4 + 1][r] = v.y;
            Bs[c4 + 2][r] = v.z; Bs[c4 + 3][r] = v.w;
        }
        __syncthreads();
        #pragma unroll 8
        for (int kk = 0; kk < BK; ++kk) {
            const float4 a4 = *(const float4*)&As[kk][m0];
            const float4 b0 = *(const float4*)&Bs[kk][n0];
            const float4 b1 = *(const float4*)&Bs[kk][n0 + 4];
            const float a[4] = {a4.x, a4.y, a4.z, a4.w};
            const float b[8] = {b0.x, b0.y, b0.z, b0.w, b1.x, b1.y, b1.z, b1.w};
            #pragma unroll
            for (int i = 0; i < 4; ++i)
                #pragma unroll
                for (int j = 0; j < 8; ++j)
                    acc[i][j] = fmaf(a[i], b[j], acc[i][j]);
        }
        __syncthreads();
    }

    #pragma unroll
    for (int i = 0; i < 4; ++i) {
        const int m = mbase + m0 + i;
        float o[8];
        #pragma unroll
        for (int j = 0; j < 8; ++j) o[j] = acc[i][j] + bias[nbase + n0 + j];
        float* p = out + (size_t)m * EMBED + nbase + n0;
        *(float4*)(p)     = make_float4(o[0], o[1], o[2], o[3]);
        *(float4*)(p + 4) = make_float4(o[4], o[5], o[6], o[7]);
    }
}

// ---------------------------------------------------------------------------
extern "C" void kernel_launch(void* const* d_in, const int* in_sizes, int n_in,
                              void* d_out, int out_size, void* d_ws, size_t ws_size,
                              hipStream_t stream)
{
    const float* x     = (const float*)d_in[0];
    const float* Wqkv  = (const float*)d_in[1];
    const float* Wout  = (const float*)d_in[2];
    const float* bout  = (const float*)d_in[3];
    const float* theta = (const float*)d_in[4];
    float* out = (float*)d_out;

    const size_t per = (size_t)4 * NHEAD * SEQ * HDIM;   // 2,097,152 floats
    float* qq      = (float*)d_ws;
    float* kq      = qq + per;
    float* vq      = kq + per;
    float* attnbuf = vq + per;

    qkv_quantum_kernel<<<dim3(32 * 24), dim3(256), 0, stream>>>(x, Wqkv, theta, qq, kq, vq);
    attn_kernel<<<dim3(256), dim3(256), 0, stream>>>(qq, kq, vq, attnbuf);
    out_gemm_kernel<<<dim3(32 * 8), dim3(256), 0, stream>>>(attnbuf, Wout, bout, out);
}